// Round 1
// baseline (384.431 us; speedup 1.0000x reference)
//
#include <hip/hip_runtime.h>
#include <hip/hip_bf16.h>

typedef __attribute__((ext_vector_type(8))) short bf16x8;
typedef __attribute__((ext_vector_type(4))) float f32x4;

#define DEVI static __device__ __forceinline__

constexpr int Bb = 4, Tt = 2048, Cc = 1024, Hh = 16;
constexpr int Mrows = Bb * Tt;       // 8192
constexpr int KVdim = 256;           // 4 kv heads * 64

DEVI unsigned short f2bf(float f) {
  union { float f; unsigned u; } v; v.f = f;
  unsigned r = v.u + 0x7fffu + ((v.u >> 16) & 1u);
  return (unsigned short)(r >> 16);
}

DEVI f32x4 mfma16(bf16x8 a, bf16x8 b, f32x4 c) {
  return __builtin_amdgcn_mfma_f32_16x16x32_bf16(a, b, c, 0, 0, 0);
}

DEVI void load_lds16(const void* g, void* s) {
  __builtin_amdgcn_global_load_lds(
      (const __attribute__((address_space(1))) void*)g,
      (__attribute__((address_space(3))) void*)s, 16, 0, 0);
}

// ---------------- fp32 -> bf16 convert ----------------
__global__ __launch_bounds__(256) void cvt_bf16(const float* __restrict__ in,
                                                unsigned short* __restrict__ out,
                                                int n) {
  int i = (blockIdx.x * 256 + threadIdx.x) * 4;
  const int stride = gridDim.x * 256 * 4;
  for (; i < n; i += stride) {
    float4 v = *(const float4*)(in + i);
    ushort4 o;
    o.x = f2bf(v.x); o.y = f2bf(v.y); o.z = f2bf(v.z); o.w = f2bf(v.w);
    *(ushort4*)(out + i) = o;
  }
}

// ---------------- NT GEMM: C[M,N] = A[M,K] . B[N,K]^T + bias ----------------
// MODE 0: bf16 out, (acc+bias)*colscale[col/64]*0.125   (Q projection)
// MODE 1: bf16 out, acc+bias                            (K/V projection)
// MODE 2: fp32 out, acc+bias                            (O projection)
template <int MODE>
__global__ __launch_bounds__(256) void gemm_nt(const short* __restrict__ A,
                                               const short* __restrict__ Bw,
                                               const float* __restrict__ bias,
                                               void* __restrict__ Cout,
                                               const float* __restrict__ colscale,
                                               int M, int N, int K) {
  __shared__ __align__(16) short As[128 * 64];
  __shared__ __align__(16) short Bs[128 * 64];
  const int tid = threadIdx.x;
  const int w = tid >> 6, l = tid & 63;
  const int l15 = l & 15, lg = l >> 4;
  const int m0 = blockIdx.x * 128, n0 = blockIdx.y * 128;
  const int wr = (w >> 1) * 64, wc = (w & 1) * 64;

  f32x4 acc[4][4] = {};

  const short* gA = A + (size_t)(m0 + w * 32 + (l >> 3)) * K + (l & 7) * 8;
  const short* gB = Bw + (size_t)(n0 + w * 32 + (l >> 3)) * K + (l & 7) * 8;
  short* lA = As + w * 32 * 64;
  short* lB = Bs + w * 32 * 64;

  for (int k0 = 0; k0 < K; k0 += 64) {
#pragma unroll
    for (int i = 0; i < 4; ++i) {
      load_lds16(gA + (size_t)i * 8 * K, lA + i * 8 * 64);
      load_lds16(gB + (size_t)i * 8 * K, lB + i * 8 * 64);
    }
    gA += 64; gB += 64;
    __syncthreads();
    bf16x8 af[2][4], bfr[2][4];
#pragma unroll
    for (int kk = 0; kk < 2; ++kk)
#pragma unroll
      for (int i = 0; i < 4; ++i) {
        af[kk][i] = *(const bf16x8*)(As + (wr + i * 16 + l15) * 64 + kk * 32 + lg * 8);
        bfr[kk][i] = *(const bf16x8*)(Bs + (wc + i * 16 + l15) * 64 + kk * 32 + lg * 8);
      }
#pragma unroll
    for (int kk = 0; kk < 2; ++kk)
#pragma unroll
      for (int mi = 0; mi < 4; ++mi)
#pragma unroll
        for (int ni = 0; ni < 4; ++ni)
          acc[mi][ni] = mfma16(af[kk][mi], bfr[kk][ni], acc[mi][ni]);
    __syncthreads();
  }

  const int crow = m0 + wr + lg * 4;
  const int ccol = n0 + wc + l15;
#pragma unroll
  for (int ni = 0; ni < 4; ++ni) {
    const int col = ccol + ni * 16;
    const float bv = bias[col];
    float sc = 1.f;
    if (MODE == 0) sc = colscale[col >> 6] * 0.125f;
#pragma unroll
    for (int mi = 0; mi < 4; ++mi) {
#pragma unroll
      for (int r = 0; r < 4; ++r) {
        const int row = crow + mi * 16 + r;
        float v = acc[mi][ni][r] + bv;
        if (MODE == 0) v *= sc;
        if (MODE == 2)
          ((float*)Cout)[(size_t)row * N + col] = v;
        else
          ((unsigned short*)Cout)[(size_t)row * N + col] = f2bf(v);
      }
    }
  }
}

// ---------------- flash attention ----------------
// grid: (T/64, B*H). block: 256 threads = 4 waves, wave w owns q rows q0+w*16..+15.
// q pre-scaled by gain/sqrt(hd) in projection epilogue.
__global__ __launch_bounds__(256) void attn_kernel(const short* __restrict__ qb,
                                                   const short* __restrict__ kb,
                                                   const short* __restrict__ vb,
                                                   unsigned short* __restrict__ ob) {
  __shared__ __align__(16) short Ks[64][72];
  __shared__ __align__(16) short Vt[64][72];   // Vt[d][s]
  __shared__ __align__(16) short Ps[4][16][72];

  const int tid = threadIdx.x, w = tid >> 6, l = tid & 63;
  const int l15 = l & 15, lg = l >> 4;
  const int q0 = blockIdx.x * 64;
  const int bh = blockIdx.y;
  const int b = bh >> 4, h = bh & 15, kv = h >> 2;

  // Q fragments (held in registers for the whole kernel)
  const short* qptr = qb + (size_t)(b * Tt + q0 + w * 16 + l15) * Cc + h * 64;
  const bf16x8 qf0 = *(const bf16x8*)(qptr + lg * 8);
  const bf16x8 qf1 = *(const bf16x8*)(qptr + 32 + lg * 8);

  float m_r[4], l_r[4];
  f32x4 oacc[4];
#pragma unroll
  for (int r = 0; r < 4; ++r) { m_r[r] = -1e30f; l_r[r] = 0.f; }
#pragma unroll
  for (int d4 = 0; d4 < 4; ++d4) oacc[d4] = f32x4{0.f, 0.f, 0.f, 0.f};

  const short* kbase = kb + (size_t)(b * Tt) * KVdim + kv * 64;
  const short* vbase = vb + (size_t)(b * Tt) * KVdim + kv * 64;

  const int ntiles = q0 / 64 + 1;
  for (int t = 0; t < ntiles; ++t) {
    const int s0 = t * 64;
    {
      // stage K tile [64 s][64 d] and V^T tile [64 d][64 s]
      const int row = tid >> 2, seg = (tid & 3) * 16;
      const short* ksrc = kbase + (size_t)(s0 + row) * KVdim + seg;
      *(bf16x8*)&Ks[row][seg] = *(const bf16x8*)ksrc;
      *(bf16x8*)&Ks[row][seg + 8] = *(const bf16x8*)(ksrc + 8);
      const short* vsrc = vbase + (size_t)(s0 + row) * KVdim + seg;
      bf16x8 v0 = *(const bf16x8*)vsrc;
      bf16x8 v1 = *(const bf16x8*)(vsrc + 8);
#pragma unroll
      for (int j = 0; j < 8; ++j) {
        Vt[seg + j][row] = v0[j];
        Vt[seg + 8 + j][row] = v1[j];
      }
    }
    __syncthreads();

    // S = Q K^T  (C layout: row=(lg*4+r)=q, col=l15=s)
    f32x4 sa[4];
#pragma unroll
    for (int n4 = 0; n4 < 4; ++n4) {
      bf16x8 k0 = *(const bf16x8*)&Ks[n4 * 16 + l15][lg * 8];
      bf16x8 k1 = *(const bf16x8*)&Ks[n4 * 16 + l15][32 + lg * 8];
      f32x4 z = {0.f, 0.f, 0.f, 0.f};
      z = mfma16(qf0, k0, z);
      sa[n4] = mfma16(qf1, k1, z);
    }

    const bool diagt = (s0 == q0);
#pragma unroll
    for (int r = 0; r < 4; ++r) {
      const int qi = q0 + w * 16 + lg * 4 + r;
      float pv[4];
      float rm = -1e30f;
#pragma unroll
      for (int n4 = 0; n4 < 4; ++n4) {
        float s = sa[n4][r];
        const int si = s0 + n4 * 16 + l15;
        if (diagt && si > qi) s = -1e30f;
        pv[n4] = s;
        rm = fmaxf(rm, s);
      }
      rm = fmaxf(rm, __shfl_xor(rm, 1));
      rm = fmaxf(rm, __shfl_xor(rm, 2));
      rm = fmaxf(rm, __shfl_xor(rm, 4));
      rm = fmaxf(rm, __shfl_xor(rm, 8));
      const float mnew = fmaxf(m_r[r], rm);
      const float alpha = __expf(m_r[r] - mnew);
      m_r[r] = mnew;
      float rs = 0.f;
#pragma unroll
      for (int n4 = 0; n4 < 4; ++n4) {
        const float p = __expf(pv[n4] - mnew);
        rs += p;
        Ps[w][lg * 4 + r][n4 * 16 + l15] = (short)f2bf(p);
      }
      rs += __shfl_xor(rs, 1);
      rs += __shfl_xor(rs, 2);
      rs += __shfl_xor(rs, 4);
      rs += __shfl_xor(rs, 8);
      l_r[r] = l_r[r] * alpha + rs;
#pragma unroll
      for (int d4 = 0; d4 < 4; ++d4) oacc[d4][r] *= alpha;
    }

    // O += P V  (A = P from per-wave LDS, B = V^T rows = d)
#pragma unroll
    for (int kk = 0; kk < 2; ++kk) {
      bf16x8 pa = *(const bf16x8*)&Ps[w][l15][kk * 32 + lg * 8];
#pragma unroll
      for (int d4 = 0; d4 < 4; ++d4) {
        bf16x8 vf = *(const bf16x8*)&Vt[d4 * 16 + l15][kk * 32 + lg * 8];
        oacc[d4] = mfma16(pa, vf, oacc[d4]);
      }
    }
    __syncthreads();
  }

  // epilogue: out[b*T+q][h*64+d] = oacc / l
#pragma unroll
  for (int d4 = 0; d4 < 4; ++d4) {
#pragma unroll
    for (int r = 0; r < 4; ++r) {
      const int row = q0 + w * 16 + lg * 4 + r;
      const int col = h * 64 + d4 * 16 + l15;
      ob[(size_t)(b * Tt + row) * Cc + col] = f2bf(oacc[d4][r] / l_r[r]);
    }
  }
}

extern "C" void kernel_launch(void* const* d_in, const int* in_sizes, int n_in,
                              void* d_out, int out_size, void* d_ws, size_t ws_size,
                              hipStream_t stream) {
  (void)in_sizes; (void)n_in; (void)out_size; (void)ws_size;
  const float* x  = (const float*)d_in[0];
  const float* Wq = (const float*)d_in[1];
  const float* bq = (const float*)d_in[2];
  const float* Wk = (const float*)d_in[3];
  const float* bk = (const float*)d_in[4];
  const float* Wv = (const float*)d_in[5];
  const float* bv = (const float*)d_in[6];
  const float* Wo = (const float*)d_in[7];
  const float* bo = (const float*)d_in[8];
  const float* gain = (const float*)d_in[9];
  float* out = (float*)d_out;

  char* ws = (char*)d_ws;
  short* xb  = (short*)ws;                    ws += (size_t)Mrows * Cc * 2;
  short* qbf = (short*)ws;                    ws += (size_t)Mrows * Cc * 2;
  short* kbf = (short*)ws;                    ws += (size_t)Mrows * KVdim * 2;
  short* vbf = (short*)ws;                    ws += (size_t)Mrows * KVdim * 2;
  short* atb = (short*)ws;                    ws += (size_t)Mrows * Cc * 2;
  short* wqb = (short*)ws;                    ws += (size_t)Cc * Cc * 2;
  short* wkb = (short*)ws;                    ws += (size_t)KVdim * Cc * 2;
  short* wvb = (short*)ws;                    ws += (size_t)KVdim * Cc * 2;
  short* wob = (short*)ws;                    ws += (size_t)Cc * Cc * 2;

  cvt_bf16<<<1024, 256, 0, stream>>>(x, (unsigned short*)xb, Mrows * Cc);
  cvt_bf16<<<256, 256, 0, stream>>>(Wq, (unsigned short*)wqb, Cc * Cc);
  cvt_bf16<<<64, 256, 0, stream>>>(Wk, (unsigned short*)wkb, KVdim * Cc);
  cvt_bf16<<<64, 256, 0, stream>>>(Wv, (unsigned short*)wvb, KVdim * Cc);
  cvt_bf16<<<256, 256, 0, stream>>>(Wo, (unsigned short*)wob, Cc * Cc);

  gemm_nt<0><<<dim3(Mrows / 128, Cc / 128), 256, 0, stream>>>(
      xb, wqb, bq, qbf, gain, Mrows, Cc, Cc);
  gemm_nt<1><<<dim3(Mrows / 128, KVdim / 128), 256, 0, stream>>>(
      xb, wkb, bk, kbf, nullptr, Mrows, KVdim, Cc);
  gemm_nt<1><<<dim3(Mrows / 128, KVdim / 128), 256, 0, stream>>>(
      xb, wvb, bv, vbf, nullptr, Mrows, KVdim, Cc);

  attn_kernel<<<dim3(Tt / 64, Bb * Hh), 256, 0, stream>>>(
      qbf, kbf, vbf, (unsigned short*)atb);

  gemm_nt<2><<<dim3(Mrows / 128, Cc / 128), 256, 0, stream>>>(
      atb, wob, bo, out, nullptr, Mrows, Cc, Cc);
}

// Round 2
// 226.356 us; speedup vs baseline: 1.6984x; 1.6984x over previous
//
#include <hip/hip_runtime.h>
#include <hip/hip_bf16.h>

typedef __attribute__((ext_vector_type(8))) short bf16x8;
typedef __attribute__((ext_vector_type(4))) float f32x4;
typedef __attribute__((ext_vector_type(16))) float f32x16;
typedef __attribute__((ext_vector_type(2))) unsigned uint2v;

#define DEVI static __device__ __forceinline__

constexpr int Bb = 4, Tt = 2048, Cc = 1024, Hh = 16;
constexpr int Mrows = Bb * Tt;       // 8192
constexpr int KVdim = 256;           // 4 kv heads * 64

DEVI unsigned short f2bf(float f) {
  union { float f; unsigned u; } v; v.f = f;
  unsigned r = v.u + 0x7fffu + ((v.u >> 16) & 1u);
  return (unsigned short)(r >> 16);
}

DEVI f32x4 mfma16(bf16x8 a, bf16x8 b, f32x4 c) {
  return __builtin_amdgcn_mfma_f32_16x16x32_bf16(a, b, c, 0, 0, 0);
}
DEVI f32x16 mfma32(bf16x8 a, bf16x8 b, f32x16 c) {
  return __builtin_amdgcn_mfma_f32_32x32x16_bf16(a, b, c, 0, 0, 0);
}

DEVI unsigned cvtpk(float lo, float hi) {
  unsigned w;
  asm("v_cvt_pk_bf16_f32 %0, %1, %2" : "=v"(w) : "v"(lo), "v"(hi));
  return w;
}

DEVI void load_lds16(const void* g, void* s) {
  __builtin_amdgcn_global_load_lds(
      (const __attribute__((address_space(1))) void*)g,
      (__attribute__((address_space(3))) void*)s, 16, 0, 0);
}

// ---------------- fp32 -> bf16 convert ----------------
__global__ __launch_bounds__(256) void cvt_bf16(const float* __restrict__ in,
                                                unsigned short* __restrict__ out,
                                                int n) {
  int i = (blockIdx.x * 256 + threadIdx.x) * 4;
  const int stride = gridDim.x * 256 * 4;
  for (; i < n; i += stride) {
    float4 v = *(const float4*)(in + i);
    ushort4 o;
    o.x = f2bf(v.x); o.y = f2bf(v.y); o.z = f2bf(v.z); o.w = f2bf(v.w);
    *(ushort4*)(out + i) = o;
  }
}

// ---------------- NT GEMM: C[M,N] = A[M,K] . B[N,K]^T + bias ----------------
// MODE 0: bf16 out, (acc+bias)*colscale[col/64]*0.125   (Q projection)
// MODE 1: bf16 out, acc+bias                            (K projection)
// MODE 2: fp32 out, acc+bias                            (O projection)
// MODE 3: bf16 out transposed [b][kv][d][T]             (V projection)
template <int MODE>
__global__ __launch_bounds__(256) void gemm_nt(const short* __restrict__ A,
                                               const short* __restrict__ Bw,
                                               const float* __restrict__ bias,
                                               void* __restrict__ Cout,
                                               const float* __restrict__ colscale,
                                               int M, int N, int K) {
  __shared__ __align__(16) short As[128 * 64];
  __shared__ __align__(16) short Bs[128 * 64];
  const int tid = threadIdx.x;
  const int w = tid >> 6, l = tid & 63;
  const int l15 = l & 15, lg = l >> 4;
  const int m0 = blockIdx.x * 128, n0 = blockIdx.y * 128;
  const int wr = (w >> 1) * 64, wc = (w & 1) * 64;

  f32x4 acc[4][4] = {};

  const short* gA = A + (size_t)(m0 + w * 32 + (l >> 3)) * K + (l & 7) * 8;
  const short* gB = Bw + (size_t)(n0 + w * 32 + (l >> 3)) * K + (l & 7) * 8;
  short* lA = As + w * 32 * 64;
  short* lB = Bs + w * 32 * 64;

  for (int k0 = 0; k0 < K; k0 += 64) {
#pragma unroll
    for (int i = 0; i < 4; ++i) {
      load_lds16(gA + (size_t)i * 8 * K, lA + i * 8 * 64);
      load_lds16(gB + (size_t)i * 8 * K, lB + i * 8 * 64);
    }
    gA += 64; gB += 64;
    __syncthreads();
    bf16x8 af[2][4], bfr[2][4];
#pragma unroll
    for (int kk = 0; kk < 2; ++kk)
#pragma unroll
      for (int i = 0; i < 4; ++i) {
        af[kk][i] = *(const bf16x8*)(As + (wr + i * 16 + l15) * 64 + kk * 32 + lg * 8);
        bfr[kk][i] = *(const bf16x8*)(Bs + (wc + i * 16 + l15) * 64 + kk * 32 + lg * 8);
      }
#pragma unroll
    for (int kk = 0; kk < 2; ++kk)
#pragma unroll
      for (int mi = 0; mi < 4; ++mi)
#pragma unroll
        for (int ni = 0; ni < 4; ++ni)
          acc[mi][ni] = mfma16(af[kk][mi], bfr[kk][ni], acc[mi][ni]);
    __syncthreads();
  }

  const int crow = m0 + wr + lg * 4;
  const int ccol = n0 + wc + l15;
#pragma unroll
  for (int ni = 0; ni < 4; ++ni) {
    const int col = ccol + ni * 16;
    const float bv = bias[col];
    float sc = 1.f;
    if (MODE == 0) sc = colscale[col >> 6] * 0.125f;
#pragma unroll
    for (int mi = 0; mi < 4; ++mi) {
#pragma unroll
      for (int r = 0; r < 4; ++r) {
        const int row = crow + mi * 16 + r;
        float v = acc[mi][ni][r] + bv;
        if (MODE == 0) v *= sc;
        if (MODE == 2) {
          ((float*)Cout)[(size_t)row * N + col] = v;
        } else if (MODE == 3) {
          const int tt = row & (Tt - 1);
          const int bb = row >> 11;
          const int kvh = col >> 6;
          const int dd = col & 63;
          ((unsigned short*)Cout)[((size_t)((bb * 4 + kvh) * 64 + dd)) * Tt + tt] = f2bf(v);
        } else {
          ((unsigned short*)Cout)[(size_t)row * N + col] = f2bf(v);
        }
      }
    }
  }
}

// ---------------- flash attention, swapped-operand 32x32 ----------------
// grid (16, B*H); block 256 = 4 waves; wave owns 32 q rows; KVBLK=64.
// S^T = mfma32(K, Q): lane holds col q=l&31, rows s. Softmax in-register.
// O^T = mfma32(Vt, P): lane holds col q=l&31, rows d -> alpha is lane-scalar.
#define PACK_SUB(pp, dst)                                        \
  {                                                              \
    unsigned Aw = cvtpk(pp[0], pp[1]), Bw_ = cvtpk(pp[2], pp[3]);\
    unsigned Cw = cvtpk(pp[4], pp[5]), Dw = cvtpk(pp[6], pp[7]); \
    uint2v xc = __builtin_amdgcn_permlane32_swap(Aw, Cw, false, false); \
    uint2v yd = __builtin_amdgcn_permlane32_swap(Bw_, Dw, false, false);\
    dst[0] = xc[0]; dst[1] = yd[0]; dst[2] = xc[1]; dst[3] = yd[1];     \
    Aw = cvtpk(pp[8], pp[9]); Bw_ = cvtpk(pp[10], pp[11]);       \
    Cw = cvtpk(pp[12], pp[13]); Dw = cvtpk(pp[14], pp[15]);      \
    xc = __builtin_amdgcn_permlane32_swap(Aw, Cw, false, false); \
    yd = __builtin_amdgcn_permlane32_swap(Bw_, Dw, false, false);\
    dst[4] = xc[0]; dst[5] = yd[0]; dst[6] = xc[1]; dst[7] = yd[1];     \
  }

__global__ __launch_bounds__(256) void attn2(const short* __restrict__ qb,
                                             const short* __restrict__ kb,
                                             const short* __restrict__ vtg,
                                             unsigned short* __restrict__ ob) {
  __shared__ __align__(16) short Ks[64][72];
  __shared__ __align__(16) short Vt[64][72];

  const int tid = threadIdx.x, w = tid >> 6, l = tid & 63;
  const int l31 = l & 31, hi = l >> 5;
  const int bh = blockIdx.y, b = bh >> 4, h = bh & 15, kv = h >> 2;
  const int bx = (blockIdx.x + bh) & 15;        // triangular load-balance remap
  const int q0 = bx * 128, qw0 = q0 + w * 32;
  const int q_abs = qw0 + l31;

  // Q fragments: B-operand of mfma32, chunk c: d = 16c + 8*hi + j
  const short* qp = qb + (size_t)(b * Tt + q_abs) * Cc + h * 64 + hi * 8;
  bf16x8 qf[4];
#pragma unroll
  for (int c = 0; c < 4; ++c) qf[c] = *(const bf16x8*)(qp + c * 16);

  f32x16 ot[2] = {};
  float m_s = -1e30f, l_s = 0.f;

  const short* kb0 = kb + (size_t)(b * Tt) * KVdim + kv * 64;
  const short* vb0 = vtg + (size_t)((b * 4 + kv) * 64) * Tt;

  const int srow = tid >> 2, scol = (tid & 3) * 16;
  const int ntiles = 2 * bx + 2;
  for (int t = 0; t < ntiles; ++t) {
    const int s0 = t * 64;
    {
      const short* ks = kb0 + (size_t)(s0 + srow) * KVdim + scol;
      *(bf16x8*)&Ks[srow][scol] = *(const bf16x8*)ks;
      *(bf16x8*)&Ks[srow][scol + 8] = *(const bf16x8*)(ks + 8);
      const short* vs = vb0 + (size_t)srow * Tt + s0 + scol;
      *(bf16x8*)&Vt[srow][scol] = *(const bf16x8*)vs;
      *(bf16x8*)&Vt[srow][scol + 8] = *(const bf16x8*)(vs + 8);
    }
    __syncthreads();

    if (s0 <= qw0 + 31) {   // wave has unmasked work in this tile
      // S^T: lane = (col q=l31), rows s = (r&3)+8*(r>>2)+4*hi (+32 for sa1)
      f32x16 sa0 = {}, sa1 = {};
#pragma unroll
      for (int c = 0; c < 4; ++c) {
        bf16x8 ka0 = *(const bf16x8*)&Ks[l31][c * 16 + hi * 8];
        bf16x8 ka1 = *(const bf16x8*)&Ks[32 + l31][c * 16 + hi * 8];
        sa0 = mfma32(ka0, qf[c], sa0);
        sa1 = mfma32(ka1, qf[c], sa1);
      }
      if (s0 + 63 > qw0) {  // diagonal: apply causal mask
#pragma unroll
        for (int r = 0; r < 16; ++r) {
          const int sl = s0 + (r & 3) + 8 * (r >> 2) + 4 * hi;
          if (sl > q_abs) sa0[r] = -1e30f;
          if (sl + 32 > q_abs) sa1[r] = -1e30f;
        }
      }
      float rm = -1e30f;
#pragma unroll
      for (int r = 0; r < 16; ++r) rm = fmaxf(rm, fmaxf(sa0[r], sa1[r]));
      rm = fmaxf(rm, __shfl_xor(rm, 32));
      const float mnew = fmaxf(m_s, rm);
      const float alpha = __expf(m_s - mnew);
      m_s = mnew;
      float p0[16], p1[16];
      float rs = 0.f;
#pragma unroll
      for (int r = 0; r < 16; ++r) {
        p0[r] = __expf(sa0[r] - mnew);
        p1[r] = __expf(sa1[r] - mnew);
        rs += p0[r] + p1[r];
      }
      rs += __shfl_xor(rs, 32);
      l_s = l_s * alpha + rs;
#pragma unroll
      for (int r = 0; r < 16; ++r) { ot[0][r] *= alpha; ot[1][r] *= alpha; }

      // pack P into PV B-fragments (T12: cvt_pk + permlane32_swap)
      unsigned pw[16];
      PACK_SUB(p0, (&pw[0]));
      PACK_SUB(p1, (&pw[8]));

      // O^T += Vt-frag * P-frag over 4 k-chunks (s), 2 m-blocks (d)
#pragma unroll
      for (int t4 = 0; t4 < 4; ++t4) {
        union { unsigned u[4]; bf16x8 v; } pb;
        pb.u[0] = pw[t4 * 4 + 0]; pb.u[1] = pw[t4 * 4 + 1];
        pb.u[2] = pw[t4 * 4 + 2]; pb.u[3] = pw[t4 * 4 + 3];
#pragma unroll
        for (int mb = 0; mb < 2; ++mb) {
          bf16x8 va = *(const bf16x8*)&Vt[mb * 32 + l31][t4 * 16 + hi * 8];
          ot[mb] = mfma32(va, pb.v, ot[mb]);
        }
      }
    }
    __syncthreads();
  }

  const float inv = 1.f / l_s;
  unsigned short* op = ob + (size_t)(b * Tt + q_abs) * Cc + h * 64;
#pragma unroll
  for (int mb = 0; mb < 2; ++mb)
#pragma unroll
    for (int r = 0; r < 16; ++r) {
      const int d = mb * 32 + (r & 3) + 8 * (r >> 2) + 4 * hi;
      op[d] = f2bf(ot[mb][r] * inv);
    }
}

extern "C" void kernel_launch(void* const* d_in, const int* in_sizes, int n_in,
                              void* d_out, int out_size, void* d_ws, size_t ws_size,
                              hipStream_t stream) {
  (void)in_sizes; (void)n_in; (void)out_size; (void)ws_size;
  const float* x  = (const float*)d_in[0];
  const float* Wq = (const float*)d_in[1];
  const float* bq = (const float*)d_in[2];
  const float* Wk = (const float*)d_in[3];
  const float* bk = (const float*)d_in[4];
  const float* Wv = (const float*)d_in[5];
  const float* bv = (const float*)d_in[6];
  const float* Wo = (const float*)d_in[7];
  const float* bo = (const float*)d_in[8];
  const float* gain = (const float*)d_in[9];
  float* out = (float*)d_out;

  char* ws = (char*)d_ws;
  short* xb  = (short*)ws;                    ws += (size_t)Mrows * Cc * 2;
  short* qbf = (short*)ws;                    ws += (size_t)Mrows * Cc * 2;
  short* kbf = (short*)ws;                    ws += (size_t)Mrows * KVdim * 2;
  short* vtg = (short*)ws;                    ws += (size_t)Mrows * KVdim * 2;
  short* atb = (short*)ws;                    ws += (size_t)Mrows * Cc * 2;
  short* wqb = (short*)ws;                    ws += (size_t)Cc * Cc * 2;
  short* wkb = (short*)ws;                    ws += (size_t)KVdim * Cc * 2;
  short* wvb = (short*)ws;                    ws += (size_t)KVdim * Cc * 2;
  short* wob = (short*)ws;                    ws += (size_t)Cc * Cc * 2;

  cvt_bf16<<<1024, 256, 0, stream>>>(x, (unsigned short*)xb, Mrows * Cc);
  cvt_bf16<<<256, 256, 0, stream>>>(Wq, (unsigned short*)wqb, Cc * Cc);
  cvt_bf16<<<64, 256, 0, stream>>>(Wk, (unsigned short*)wkb, KVdim * Cc);
  cvt_bf16<<<64, 256, 0, stream>>>(Wv, (unsigned short*)wvb, KVdim * Cc);
  cvt_bf16<<<256, 256, 0, stream>>>(Wo, (unsigned short*)wob, Cc * Cc);

  gemm_nt<0><<<dim3(Mrows / 128, Cc / 128), 256, 0, stream>>>(
      xb, wqb, bq, qbf, gain, Mrows, Cc, Cc);
  gemm_nt<1><<<dim3(Mrows / 128, KVdim / 128), 256, 0, stream>>>(
      xb, wkb, bk, kbf, nullptr, Mrows, KVdim, Cc);
  gemm_nt<3><<<dim3(Mrows / 128, KVdim / 128), 256, 0, stream>>>(
      xb, wvb, bv, vtg, nullptr, Mrows, KVdim, Cc);

  attn2<<<dim3(16, Bb * Hh), 256, 0, stream>>>(
      qbf, kbf, vtg, (unsigned short*)atb);

  gemm_nt<2><<<dim3(Mrows / 128, Cc / 128), 256, 0, stream>>>(
      atb, wob, bo, out, nullptr, Mrows, Cc, Cc);
}